// Round 1
// baseline (361.842 us; speedup 1.0000x reference)
//
#include <hip/hip_runtime.h>
#include <hip/hip_bf16.h>
#include <math.h>

#define B_ 32
#define T_ 2000
#define DE_ 512
#define DD_ 1024
#define A_ 128
#define FN_ 32
#define FS_ 16
#define KW_ (2*FS_+1)   // 33

typedef __bf16 bf16x8 __attribute__((ext_vector_type(8)));
typedef float f32x4 __attribute__((ext_vector_type(4)));

#define BT 64            // t-rows per block
#define KC 64            // K chunk staged in LDS
#define ASTR (KC + 8)    // padded LDS row stride (bf16 elems) -> bank-conflict-free-ish

// Manual LDS overlay (bytes):
//  R1 [0, 9216):        Atile (64 x 72 bf16)      / loc_s (64 x 32 f32 = 8192)
//  R2 [9216, 30208):    Btile (128 x 72 bf16=18432) / att_wT(16384)+cw_s(4224)+pa_s(384)
//  R3 [30208, 62976):   base_s (64 x 128 f32)
#define SZ_R1 9216
#define SZ_R2 20992
#define OFF_BTILE SZ_R1
#define OFF_BASE (SZ_R1 + SZ_R2)
#define SMEM_TOTAL (OFF_BASE + BT * A_ * 4)   // 62976 < 64 KiB

// ---------------------------------------------------------------------------
// Kernel 0: projected_dec[b][a] = sum_d input_dec[b][d] * dec_w[a][d]
// ---------------------------------------------------------------------------
__global__ __launch_bounds__(256) void pdec_kernel(
    const float* __restrict__ input_dec, const float* __restrict__ dec_w,
    float* __restrict__ pdec)
{
    int b = blockIdx.x;
    int tid = threadIdx.x;
    int a = tid & 127;
    int h = tid >> 7;                 // 0 or 1 (half of K)
    const float4* w = (const float4*)(dec_w + (size_t)a * DD_ + h * 512);
    const float4* x = (const float4*)(input_dec + (size_t)b * DD_ + h * 512);
    float acc = 0.f;
    #pragma unroll 8
    for (int i = 0; i < 128; i++) {
        float4 wv = w[i], xv = x[i];
        acc += wv.x * xv.x + wv.y * xv.y + wv.z * xv.z + wv.w * xv.w;
    }
    __shared__ float sm[256];
    sm[tid] = acc;
    __syncthreads();
    if (tid < 128) pdec[b * A_ + tid] = sm[tid] + sm[tid + 128];
}

// ---------------------------------------------------------------------------
// Kernel 1: fused conv + att-proj + enc-proj (bf16 MFMA) + tanh + out_w dot
// One block = (b, 64 t-rows). Writes score[b][t].
// ---------------------------------------------------------------------------
__global__ __launch_bounds__(256) void score_kernel(
    const float* __restrict__ input_enc, const float* __restrict__ enc_w,
    const float* __restrict__ prev_att,  const float* __restrict__ conv_w,
    const float* __restrict__ att_w,     const float* __restrict__ att_b,
    const float* __restrict__ out_w,     const float* __restrict__ pdec,
    float* __restrict__ score)
{
    __shared__ __align__(16) char smem[SMEM_TOTAL];
    __bf16* Atile = (__bf16*)(smem);
    __bf16* Btile = (__bf16*)(smem + OFF_BTILE);
    float*  base_s = (float*)(smem + OFF_BASE);
    float*  loc_s  = (float*)(smem);                       // overlays Atile
    float*  att_wT = (float*)(smem + OFF_BTILE);           // overlays Btile
    float*  cw_s   = (float*)(smem + OFF_BTILE + 16384);
    float*  pa_s   = (float*)(smem + OFF_BTILE + 16384 + 4224);

    const int tid = threadIdx.x;
    const int b  = blockIdx.y;
    const int t0 = blockIdx.x * BT;

    // ---- phase 0: stage small params ----
    for (int idx = tid; idx < A_ * FN_; idx += 256) {        // att_w [A,FN] -> [f][a]
        int a = idx >> 5, f = idx & 31;
        att_wT[f * A_ + a] = att_w[idx];
    }
    for (int idx = tid; idx < FN_ * KW_; idx += 256) {       // conv_w [f][k] -> [k][f]
        int f = idx / KW_, k = idx % KW_;
        cw_s[k * FN_ + f] = conv_w[idx];
    }
    for (int j = tid; j < BT + 2 * FS_; j += 256) {          // prev_att halo
        int t = t0 - FS_ + j;
        pa_s[j] = (t >= 0 && t < T_) ? prev_att[b * T_ + t] : 0.f;
    }
    __syncthreads();

    // ---- phase 1: conv -> loc_s[r][f] ----
    {
        int f = tid & 31;
        int r0 = tid >> 5;
        for (int r = r0; r < BT; r += 8) {
            float acc = 0.f;
            #pragma unroll
            for (int k = 0; k < KW_; k++) acc += pa_s[r + k] * cw_s[k * FN_ + f];
            loc_s[r * FN_ + f] = acc;
        }
    }
    __syncthreads();

    // ---- phase 2: base_s[r][a] = att_b[a] + pdec[b][a] + loc . att_w ----
    {
        int a = tid & 127;
        int r0 = tid >> 7;
        float bias = att_b[a] + pdec[b * A_ + a];
        for (int r = r0; r < BT; r += 2) {
            float v = bias;
            #pragma unroll
            for (int f = 0; f < FN_; f++) v += loc_s[r * FN_ + f] * att_wT[f * A_ + a];
            base_s[r * A_ + a] = v;
        }
    }
    __syncthreads();   // loc_s / att_wT dead after this; Atile/Btile may overwrite

    // ---- phase 3: MFMA K-loop ----
    f32x4 acc[8];
    #pragma unroll
    for (int i = 0; i < 8; i++) acc[i] = (f32x4){0.f, 0.f, 0.f, 0.f};

    const int lane = tid & 63;
    const int wv   = tid >> 6;       // wave 0..3 -> rows wv*16 .. wv*16+15
    const int col  = lane & 15;
    const int grp  = lane >> 4;

    for (int kc = 0; kc < DE_; kc += KC) {
        // stage A (enc rows) and B (enc_w rows), fp32 -> bf16
        {
            int c4 = tid & 15;       // float4 column
            int r0 = tid >> 4;       // 0..15
            for (int r = r0; r < BT; r += 16) {
                int t = t0 + r;
                float4 v = make_float4(0.f, 0.f, 0.f, 0.f);
                if (t < T_)
                    v = ((const float4*)(input_enc + (size_t)(b * T_ + t) * DE_ + kc))[c4];
                __bf16* dst = Atile + r * ASTR + c4 * 4;
                dst[0] = (__bf16)v.x; dst[1] = (__bf16)v.y;
                dst[2] = (__bf16)v.z; dst[3] = (__bf16)v.w;
            }
            for (int a = r0; a < A_; a += 16) {
                float4 v = ((const float4*)(enc_w + (size_t)a * DE_ + kc))[c4];
                __bf16* dst = Btile + a * ASTR + c4 * 4;
                dst[0] = (__bf16)v.x; dst[1] = (__bf16)v.y;
                dst[2] = (__bf16)v.z; dst[3] = (__bf16)v.w;
            }
        }
        __syncthreads();
        #pragma unroll
        for (int ks = 0; ks < KC / 32; ks++) {
            int kb = ks * 32 + grp * 8;
            bf16x8 afrag = *(const bf16x8*)(Atile + (wv * 16 + col) * ASTR + kb);
            #pragma unroll
            for (int i = 0; i < 8; i++) {
                bf16x8 bfrag = *(const bf16x8*)(Btile + (i * 16 + col) * ASTR + kb);
                acc[i] = __builtin_amdgcn_mfma_f32_16x16x32_bf16(afrag, bfrag, acc[i], 0, 0, 0);
            }
        }
        __syncthreads();
    }

    // ---- phase 4: epilogue: tanh(acc + base) . out_w, reduce over a ----
    float s[4] = {0.f, 0.f, 0.f, 0.f};
    #pragma unroll
    for (int i = 0; i < 8; i++) {
        int a = i * 16 + col;
        float ow = out_w[a];
        #pragma unroll
        for (int r = 0; r < 4; r++) {
            int row = wv * 16 + grp * 4 + r;
            float v = acc[i][r] + base_s[row * A_ + a];
            s[r] += ow * tanhf(v);
        }
    }
    #pragma unroll
    for (int r = 0; r < 4; r++) {
        s[r] += __shfl_xor(s[r], 1, 64);
        s[r] += __shfl_xor(s[r], 2, 64);
        s[r] += __shfl_xor(s[r], 4, 64);
        s[r] += __shfl_xor(s[r], 8, 64);
    }
    if (col == 0) {
        #pragma unroll
        for (int r = 0; r < 4; r++) {
            int t = t0 + wv * 16 + grp * 4 + r;
            if (t < T_) score[b * T_ + t] = s[r];
        }
    }
}

// ---------------------------------------------------------------------------
// Kernel 2: masked softmax over t per batch; writes att_weight to d_out
// ---------------------------------------------------------------------------
__global__ __launch_bounds__(256) void softmax_kernel(
    const float* __restrict__ score, const int* __restrict__ lengths,
    float* __restrict__ att)
{
    int b = blockIdx.x;
    int tid = threadIdx.x;
    int len = lengths[b];
    __shared__ float redm[4], reds[4];

    float m = -1e30f;
    for (int t = tid; t < T_; t += 256)
        if (t < len) m = fmaxf(m, score[b * T_ + t]);
    #pragma unroll
    for (int off = 1; off < 64; off <<= 1) m = fmaxf(m, __shfl_xor(m, off, 64));
    if ((tid & 63) == 0) redm[tid >> 6] = m;
    __syncthreads();
    m = fmaxf(fmaxf(redm[0], redm[1]), fmaxf(redm[2], redm[3]));

    float sum = 0.f;
    for (int t = tid; t < T_; t += 256)
        if (t < len) sum += expf(score[b * T_ + t] - m);
    #pragma unroll
    for (int off = 1; off < 64; off <<= 1) sum += __shfl_xor(sum, off, 64);
    if ((tid & 63) == 0) reds[tid >> 6] = sum;
    __syncthreads();
    sum = reds[0] + reds[1] + reds[2] + reds[3];
    float inv = 1.f / sum;

    for (int t = tid; t < T_; t += 256) {
        float w = (t < len) ? expf(score[b * T_ + t] - m) * inv : 0.f;
        att[b * T_ + t] = w;
    }
}

// ---------------------------------------------------------------------------
// Kernel 3: context[b][d] = sum_t att[b][t] * enc[b][t][d]  (atomic partials)
// grid: (16 t-chunks of 125, B)
// ---------------------------------------------------------------------------
__global__ __launch_bounds__(256) void context_kernel(
    const float* __restrict__ enc, const float* __restrict__ att,
    float* __restrict__ ctx)
{
    int b = blockIdx.y;
    int tid = threadIdx.x;
    int d0 = tid * 2;
    int tstart = blockIdx.x * (T_ / 16);
    int tend = tstart + (T_ / 16);
    float ax = 0.f, ay = 0.f;
    for (int t = tstart; t < tend; t++) {
        float w = att[b * T_ + t];
        if (w != 0.f) {
            float2 v = *(const float2*)(enc + (size_t)(b * T_ + t) * DE_ + d0);
            ax += w * v.x;
            ay += w * v.y;
        }
    }
    atomicAdd(&ctx[b * DE_ + d0], ax);
    atomicAdd(&ctx[b * DE_ + d0 + 1], ay);
}

// ---------------------------------------------------------------------------
extern "C" void kernel_launch(void* const* d_in, const int* in_sizes, int n_in,
                              void* d_out, int out_size, void* d_ws, size_t ws_size,
                              hipStream_t stream)
{
    const float* input_enc   = (const float*)d_in[0];
    const int*   enc_lengths = (const int*)d_in[1];
    const float* input_dec   = (const float*)d_in[2];
    const float* prev_att    = (const float*)d_in[3];
    const float* conv_w      = (const float*)d_in[4];
    const float* enc_w       = (const float*)d_in[5];
    const float* dec_w       = (const float*)d_in[6];
    const float* att_w       = (const float*)d_in[7];
    const float* att_b       = (const float*)d_in[8];
    const float* out_w       = (const float*)d_in[9];

    float* out = (float*)d_out;                 // [0:B*DE) context, [B*DE:) att_weight
    float* ws_f = (float*)d_ws;
    float* pdec  = ws_f;                        // B*A = 4096 floats
    float* score = ws_f + B_ * A_;              // B*T = 64000 floats

    // zero the context region (accumulated via atomics)
    hipMemsetAsync(d_out, 0, (size_t)B_ * DE_ * sizeof(float), stream);

    pdec_kernel<<<B_, 256, 0, stream>>>(input_dec, dec_w, pdec);

    dim3 sgrid((T_ + BT - 1) / BT, B_);
    score_kernel<<<sgrid, 256, 0, stream>>>(input_enc, enc_w, prev_att, conv_w,
                                            att_w, att_b, out_w, pdec, score);

    softmax_kernel<<<B_, 256, 0, stream>>>(score, enc_lengths, out + B_ * DE_);

    dim3 cgrid(16, B_);
    context_kernel<<<cgrid, 256, 0, stream>>>(input_enc, out + B_ * DE_, out);
}

// Round 2
// 276.611 us; speedup vs baseline: 1.3081x; 1.3081x over previous
//
#include <hip/hip_runtime.h>
#include <hip/hip_bf16.h>
#include <math.h>

#define B_ 32
#define T_ 2000
#define DE_ 512
#define DD_ 1024
#define A_ 128
#define FN_ 32
#define FS_ 16
#define KW_ (2*FS_+1)   // 33

typedef __bf16 bf16x8 __attribute__((ext_vector_type(8)));
typedef __bf16 bf16x4 __attribute__((ext_vector_type(4)));
typedef float f32x4 __attribute__((ext_vector_type(4)));

#define BT 64            // t-rows per score block
#define LSTR 40          // loc tile LDS stride (bf16): 80 B/row -> 2-way max (free)

// ---------------------------------------------------------------------------
// Kernel A: convert enc_w [A,DE] and att_w [A,FN] fp32 -> bf16 (once per call)
// grid: 64 blocks x 256 (covers 16384 float4 of enc_w; first 1024 also do att_w)
// ---------------------------------------------------------------------------
__global__ __launch_bounds__(256) void cvt_kernel(
    const float* __restrict__ enc_w, const float* __restrict__ att_w,
    __bf16* __restrict__ enc_bf, __bf16* __restrict__ att_bf)
{
    int i = blockIdx.x * 256 + threadIdx.x;       // float4 index
    float4 v = ((const float4*)enc_w)[i];
    bf16x4 o;
    o[0] = (__bf16)v.x; o[1] = (__bf16)v.y; o[2] = (__bf16)v.z; o[3] = (__bf16)v.w;
    *(bf16x4*)(enc_bf + (size_t)i * 4) = o;
    if (i < (A_ * FN_) / 4) {
        float4 w = ((const float4*)att_w)[i];
        bf16x4 p;
        p[0] = (__bf16)w.x; p[1] = (__bf16)w.y; p[2] = (__bf16)w.z; p[3] = (__bf16)w.w;
        *(bf16x4*)(att_bf + (size_t)i * 4) = p;
    }
}

// ---------------------------------------------------------------------------
// Kernel B: pdec_bias[b][a] = att_b[a] + sum_d input_dec[b][d] * dec_w[a][d]
// grid: (4 a-tiles of 32, B), block 256: 8 threads per a over K
// ---------------------------------------------------------------------------
__global__ __launch_bounds__(256) void pdec_kernel(
    const float* __restrict__ input_dec, const float* __restrict__ dec_w,
    const float* __restrict__ att_b, float* __restrict__ pdec)
{
    int b  = blockIdx.y;
    int a0 = blockIdx.x * 32;
    int tid = threadIdx.x;
    int al = tid >> 3;          // 0..31
    int kg = tid & 7;           // 0..7
    int a  = a0 + al;
    const float4* w = (const float4*)(dec_w + (size_t)a * DD_);
    const float4* x = (const float4*)(input_dec + (size_t)b * DD_);
    float acc = 0.f;
    #pragma unroll 8
    for (int j = 0; j < 32; j++) {
        int i4 = kg + j * 8;
        float4 wv = w[i4], xv = x[i4];
        acc += wv.x * xv.x + wv.y * xv.y + wv.z * xv.z + wv.w * xv.w;
    }
    acc += __shfl_xor(acc, 1, 64);
    acc += __shfl_xor(acc, 2, 64);
    acc += __shfl_xor(acc, 4, 64);
    if (kg == 0) pdec[b * A_ + a] = acc + att_b[a];
}

// ---------------------------------------------------------------------------
// Kernel C: score. One block = (b, 64 t-rows). Barrier-free MFMA K-loop:
// A fragments straight from global fp32 (cvt in reg), B from bf16 enc_w (L1/L2
// hot). Location projection folded into the same accumulator via one K=32
// MFMA step. Epilogue: fast tanh + out_w dot + 16-lane shuffle reduce.
// ---------------------------------------------------------------------------
__global__ __launch_bounds__(256, 4) void score_kernel(
    const float* __restrict__ input_enc, const __bf16* __restrict__ enc_bf,
    const float* __restrict__ prev_att,  const float* __restrict__ conv_w,
    const __bf16* __restrict__ att_bf,   const float* __restrict__ pdec,
    const float* __restrict__ out_w,     float* __restrict__ score)
{
    __shared__ float pa_s[BT + 2 * FS_];     // 96
    __shared__ float cw_s[KW_ * FN_];        // 1056
    __shared__ __bf16 loc_s[BT * LSTR];      // 5120 B

    const int tid = threadIdx.x;
    const int b  = blockIdx.y;
    const int t0 = blockIdx.x * BT;

    // stage prev_att halo + conv weights (transposed [k][f])
    for (int j = tid; j < BT + 2 * FS_; j += 256) {
        int t = t0 - FS_ + j;
        pa_s[j] = (t >= 0 && t < T_) ? prev_att[b * T_ + t] : 0.f;
    }
    for (int idx = tid; idx < FN_ * KW_; idx += 256) {
        int f = idx / KW_, k = idx % KW_;
        cw_s[k * FN_ + f] = conv_w[idx];
    }
    __syncthreads();

    // conv -> loc (bf16)
    {
        int f = tid & 31, r0 = tid >> 5;
        for (int r = r0; r < BT; r += 8) {
            float acc = 0.f;
            #pragma unroll
            for (int k = 0; k < KW_; k++) acc += pa_s[r + k] * cw_s[k * FN_ + f];
            loc_s[r * LSTR + f] = (__bf16)acc;
        }
    }
    __syncthreads();

    const int lane = tid & 63;
    const int wv   = tid >> 6;
    const int col  = lane & 15;
    const int grp  = lane >> 4;
    const int rowb = wv * 16 + col;              // block-local A row (m = col)
    const int t_row = t0 + rowb;
    const int t_clamp = t_row < T_ ? t_row : T_ - 1;

    f32x4 acc[8];
    const f32x4 zero = (f32x4){0.f, 0.f, 0.f, 0.f};

    // loc-projection MFMA (K = 32 = FN_): acc = loc @ att_w^T
    {
        bf16x8 afrag = *(const bf16x8*)(loc_s + rowb * LSTR + grp * 8);
        #pragma unroll
        for (int i = 0; i < 8; i++) {
            bf16x8 bfrag = *(const bf16x8*)(att_bf + (size_t)(i * 16 + col) * FN_ + grp * 8);
            acc[i] = __builtin_amdgcn_mfma_f32_16x16x32_bf16(afrag, bfrag, zero, 0, 0, 0);
        }
    }

    // enc-projection MFMA K-loop, no barriers
    const float* arow = input_enc + ((size_t)(b * T_ + t_clamp)) * DE_ + grp * 8;
    const __bf16* bbase = enc_bf + (size_t)col * DE_ + grp * 8;
    #pragma unroll 2
    for (int kc = 0; kc < DE_; kc += 32) {
        float4 a0v = *(const float4*)(arow + kc);
        float4 a1v = *(const float4*)(arow + kc + 4);
        bf16x8 afrag;
        afrag[0] = (__bf16)a0v.x; afrag[1] = (__bf16)a0v.y;
        afrag[2] = (__bf16)a0v.z; afrag[3] = (__bf16)a0v.w;
        afrag[4] = (__bf16)a1v.x; afrag[5] = (__bf16)a1v.y;
        afrag[6] = (__bf16)a1v.z; afrag[7] = (__bf16)a1v.w;
        #pragma unroll
        for (int i = 0; i < 8; i++) {
            bf16x8 bfrag = *(const bf16x8*)(bbase + (size_t)i * 16 * DE_ + kc);
            acc[i] = __builtin_amdgcn_mfma_f32_16x16x32_bf16(afrag, bfrag, acc[i], 0, 0, 0);
        }
    }

    // epilogue: tanh(acc + bias) . out_w, reduce over a (col lanes)
    float s[4] = {0.f, 0.f, 0.f, 0.f};
    #pragma unroll
    for (int i = 0; i < 8; i++) {
        int a = i * 16 + col;
        float ow = out_w[a];
        float bias = pdec[b * A_ + a];
        #pragma unroll
        for (int r = 0; r < 4; r++) {
            float v = acc[i][r] + bias;
            v = fminf(fmaxf(v, -15.f), 15.f);
            float e = __expf(2.f * v);
            s[r] += ow * ((e - 1.f) / (e + 1.f));
        }
    }
    #pragma unroll
    for (int r = 0; r < 4; r++) {
        s[r] += __shfl_xor(s[r], 1, 64);
        s[r] += __shfl_xor(s[r], 2, 64);
        s[r] += __shfl_xor(s[r], 4, 64);
        s[r] += __shfl_xor(s[r], 8, 64);
    }
    if (col == 0) {
        #pragma unroll
        for (int r = 0; r < 4; r++) {
            int t = t0 + wv * 16 + grp * 4 + r;
            if (t < T_) score[b * T_ + t] = s[r];
        }
    }
}

// ---------------------------------------------------------------------------
// Kernel D: masked softmax over t per batch; writes att_weight to d_out
// ---------------------------------------------------------------------------
__global__ __launch_bounds__(256) void softmax_kernel(
    const float* __restrict__ score, const int* __restrict__ lengths,
    float* __restrict__ att)
{
    int b = blockIdx.x;
    int tid = threadIdx.x;
    int len = lengths[b];
    __shared__ float redm[4], reds[4];

    float m = -1e30f;
    for (int t = tid; t < T_; t += 256)
        if (t < len) m = fmaxf(m, score[b * T_ + t]);
    #pragma unroll
    for (int off = 1; off < 64; off <<= 1) m = fmaxf(m, __shfl_xor(m, off, 64));
    if ((tid & 63) == 0) redm[tid >> 6] = m;
    __syncthreads();
    m = fmaxf(fmaxf(redm[0], redm[1]), fmaxf(redm[2], redm[3]));

    float sum = 0.f;
    for (int t = tid; t < T_; t += 256)
        if (t < len) sum += expf(score[b * T_ + t] - m);
    #pragma unroll
    for (int off = 1; off < 64; off <<= 1) sum += __shfl_xor(sum, off, 64);
    if ((tid & 63) == 0) reds[tid >> 6] = sum;
    __syncthreads();
    sum = reds[0] + reds[1] + reds[2] + reds[3];
    float inv = 1.f / sum;

    for (int t = tid; t < T_; t += 256) {
        float w = (t < len) ? expf(score[b * T_ + t] - m) * inv : 0.f;
        att[b * T_ + t] = w;
    }
}

// ---------------------------------------------------------------------------
// Kernel E: context[b][d] = sum_t att[b][t] * enc[b][t][d]
// grid (16 t-chunks of 125, B); att staged in LDS, t clamped to len ->
// unconditional pipelined row loads.
// ---------------------------------------------------------------------------
#define CT 125
__global__ __launch_bounds__(256) void context_kernel(
    const float* __restrict__ enc, const float* __restrict__ att,
    const int* __restrict__ lengths, float* __restrict__ ctx)
{
    int b = blockIdx.y;
    int tstart = blockIdx.x * CT;
    int len = lengths[b];
    int tend = tstart + CT < len ? tstart + CT : len;
    __shared__ float w_s[CT];
    for (int j = threadIdx.x; j < CT; j += 256) w_s[j] = att[b * T_ + tstart + j];
    __syncthreads();
    if (tstart >= tend) return;

    int d0 = threadIdx.x * 2;
    const float* base = enc + ((size_t)(b * T_ + tstart)) * DE_ + d0;
    float ax = 0.f, ay = 0.f;
    int n = tend - tstart;
    #pragma unroll 4
    for (int t = 0; t < n; t++) {
        float w = w_s[t];
        float2 v = *(const float2*)(base + (size_t)t * DE_);
        ax += w * v.x;
        ay += w * v.y;
    }
    atomicAdd(&ctx[b * DE_ + d0], ax);
    atomicAdd(&ctx[b * DE_ + d0 + 1], ay);
}

// ---------------------------------------------------------------------------
extern "C" void kernel_launch(void* const* d_in, const int* in_sizes, int n_in,
                              void* d_out, int out_size, void* d_ws, size_t ws_size,
                              hipStream_t stream)
{
    const float* input_enc   = (const float*)d_in[0];
    const int*   enc_lengths = (const int*)d_in[1];
    const float* input_dec   = (const float*)d_in[2];
    const float* prev_att    = (const float*)d_in[3];
    const float* conv_w      = (const float*)d_in[4];
    const float* enc_w       = (const float*)d_in[5];
    const float* dec_w       = (const float*)d_in[6];
    const float* att_w       = (const float*)d_in[7];
    const float* att_b       = (const float*)d_in[8];
    const float* out_w       = (const float*)d_in[9];

    float* out = (float*)d_out;                 // [0:B*DE) context, [B*DE:) att_weight
    char* ws = (char*)d_ws;
    float*  pdec   = (float*)ws;                        // B*A floats       (16 KB)
    float*  score  = (float*)(ws + 16384);              // B*T floats       (256 KB)
    __bf16* enc_bf = (__bf16*)(ws + 16384 + 256000);    // A*DE bf16        (128 KB)
    __bf16* att_bf = (__bf16*)(ws + 16384 + 256000 + 131072); // A*FN bf16  (8 KB)

    hipMemsetAsync(d_out, 0, (size_t)B_ * DE_ * sizeof(float), stream);

    cvt_kernel<<<(A_ * DE_) / 4 / 256, 256, 0, stream>>>(enc_w, att_w, enc_bf, att_bf);

    dim3 pgrid(4, B_);
    pdec_kernel<<<pgrid, 256, 0, stream>>>(input_dec, dec_w, att_b, pdec);

    dim3 sgrid((T_ + BT - 1) / BT, B_);
    score_kernel<<<sgrid, 256, 0, stream>>>(input_enc, enc_bf, prev_att, conv_w,
                                            att_bf, pdec, out_w, score);

    softmax_kernel<<<B_, 256, 0, stream>>>(score, enc_lengths, out + B_ * DE_);

    dim3 cgrid(16, B_);
    context_kernel<<<cgrid, 256, 0, stream>>>(input_enc, out + B_ * DE_, enc_lengths, out);
}

// Round 3
// 245.839 us; speedup vs baseline: 1.4719x; 1.1252x over previous
//
#include <hip/hip_runtime.h>
#include <hip/hip_bf16.h>
#include <math.h>

#define B_ 32
#define T_ 2000
#define DE_ 512
#define DD_ 1024
#define A_ 128
#define FN_ 32
#define FS_ 16
#define KW_ (2*FS_+1)   // 33

typedef __bf16 bf16x8 __attribute__((ext_vector_type(8)));
typedef __bf16 bf16x4 __attribute__((ext_vector_type(4)));
typedef float f32x4 __attribute__((ext_vector_type(4)));

#define BT 64            // t-rows per score block
#define LSTR 40          // loc tile LDS stride (bf16)

// async global->LDS, 16 B per lane; dest = lds base (wave-uniform) + lane*16
__device__ __forceinline__ void load_lds16(const void* g, void* l) {
    __builtin_amdgcn_global_load_lds(
        (const __attribute__((address_space(1))) unsigned int*)g,
        (__attribute__((address_space(3))) unsigned int*)l, 16, 0, 0);
}

// ---------------------------------------------------------------------------
// Kernel 1: prep. blocks 0..63: enc_w/att_w fp32->bf16. blocks 64..191: pdec.
// pdec[b][a] = att_b[a] + input_dec[b] . dec_w[a]
// ---------------------------------------------------------------------------
__global__ __launch_bounds__(256) void prep_kernel(
    const float* __restrict__ enc_w, const float* __restrict__ att_w,
    const float* __restrict__ input_dec, const float* __restrict__ dec_w,
    const float* __restrict__ att_b,
    __bf16* __restrict__ enc_bf, __bf16* __restrict__ att_bf,
    float* __restrict__ pdec)
{
    int bx = blockIdx.x, tid = threadIdx.x;
    if (bx < 64) {
        int i = bx * 256 + tid;                         // float4 index
        float4 v = ((const float4*)enc_w)[i];
        bf16x4 o;
        o[0] = (__bf16)v.x; o[1] = (__bf16)v.y; o[2] = (__bf16)v.z; o[3] = (__bf16)v.w;
        *(bf16x4*)(enc_bf + (size_t)i * 4) = o;
        if (i < (A_ * FN_) / 4) {
            float4 w = ((const float4*)att_w)[i];
            bf16x4 p;
            p[0] = (__bf16)w.x; p[1] = (__bf16)w.y; p[2] = (__bf16)w.z; p[3] = (__bf16)w.w;
            *(bf16x4*)(att_bf + (size_t)i * 4) = p;
        }
    } else {
        int pb = bx - 64;                               // 0..127
        int b  = pb >> 2;
        int a0 = (pb & 3) * 32;
        int al = tid >> 3;                              // 0..31
        int kg = tid & 7;                               // 0..7
        int a  = a0 + al;
        const float4* w = (const float4*)(dec_w + (size_t)a * DD_);
        const float4* x = (const float4*)(input_dec + (size_t)b * DD_);
        float acc = 0.f;
        #pragma unroll 8
        for (int j = 0; j < 32; j++) {
            int i4 = kg + j * 8;
            float4 wv = w[i4], xv = x[i4];
            acc += wv.x * xv.x + wv.y * xv.y + wv.z * xv.z + wv.w * xv.w;
        }
        acc += __shfl_xor(acc, 1, 64);
        acc += __shfl_xor(acc, 2, 64);
        acc += __shfl_xor(acc, 4, 64);
        if (kg == 0) pdec[b * A_ + a] = acc + att_b[a];
    }
}

// ---------------------------------------------------------------------------
// Kernel 2: score. One block = (b, 64 t-rows).
// B (enc_bf) chunk staged to LDS by global_load_lds w/ XOR source swizzle;
// A rows direct from global fp32 (each element read once device-wide).
// loc-projection folded into the same MFMA accumulator.
// ---------------------------------------------------------------------------
__global__ __launch_bounds__(256, 4) void score_kernel(
    const float* __restrict__ input_enc, const __bf16* __restrict__ enc_bf,
    const float* __restrict__ prev_att,  const float* __restrict__ conv_w,
    const __bf16* __restrict__ att_bf,   const float* __restrict__ pdec,
    const float* __restrict__ out_w,     float* __restrict__ score)
{
    __shared__ __align__(16) char Bt[16384];     // B chunk: 128 rows x 64 k bf16
    __shared__ float pa_s[BT + 2 * FS_];
    __shared__ float cw_s[KW_ * FN_];
    __shared__ __align__(16) __bf16 loc_s[BT * LSTR];

    const int tid = threadIdx.x;
    const int b  = blockIdx.y;
    const int t0 = blockIdx.x * BT;

    for (int j = tid; j < BT + 2 * FS_; j += 256) {
        int t = t0 - FS_ + j;
        pa_s[j] = (t >= 0 && t < T_) ? prev_att[b * T_ + t] : 0.f;
    }
    for (int idx = tid; idx < FN_ * KW_; idx += 256) {
        int f = idx / KW_, k = idx % KW_;
        cw_s[k * FN_ + f] = conv_w[idx];
    }
    __syncthreads();

    {   // conv -> loc (bf16)
        int f = tid & 31, r0 = tid >> 5;
        for (int r = r0; r < BT; r += 8) {
            float acc = 0.f;
            #pragma unroll
            for (int k = 0; k < KW_; k++) acc += pa_s[r + k] * cw_s[k * FN_ + f];
            loc_s[r * LSTR + f] = (__bf16)acc;
        }
    }
    __syncthreads();

    const int lane = tid & 63;
    const int wv   = tid >> 6;
    const int col  = lane & 15;
    const int grp  = lane >> 4;
    const int rowb = wv * 16 + col;
    const int t_row = t0 + rowb;
    const int t_clamp = t_row < T_ ? t_row : T_ - 1;
    const int sw = (col & 7);                    // XOR swizzle key for ds reads

    f32x4 acc[8];
    const f32x4 zero = (f32x4){0.f, 0.f, 0.f, 0.f};

    {   // loc-projection MFMA (K=32=FN)
        bf16x8 afrag = *(const bf16x8*)(loc_s + rowb * LSTR + grp * 8);
        #pragma unroll
        for (int i = 0; i < 8; i++) {
            bf16x8 bfrag = *(const bf16x8*)(att_bf + (size_t)(i * 16 + col) * FN_ + grp * 8);
            acc[i] = __builtin_amdgcn_mfma_f32_16x16x32_bf16(afrag, bfrag, zero, 0, 0, 0);
        }
    }

    const float* arow = input_enc + ((size_t)(b * T_ + t_clamp)) * DE_ + grp * 8;

    for (int kc = 0; kc < DE_; kc += 64) {
        // stage B chunk: slot s covers LDS [s*16, s*16+16) = row r, phys chunk
        // cp; source = logical chunk c = cp ^ (r&7)  (XOR bank swizzle)
        #pragma unroll
        for (int j = 0; j < 4; j++) {
            int s  = j * 256 + tid;
            int r  = s >> 3;
            int cp = s & 7;
            int c  = cp ^ (r & 7);
            load_lds16(enc_bf + (size_t)r * DE_ + kc + c * 8,
                       Bt + j * 4096 + wv * 1024);
        }
        float4 a00 = *(const float4*)(arow + kc);
        float4 a01 = *(const float4*)(arow + kc + 4);
        float4 a10 = *(const float4*)(arow + kc + 32);
        float4 a11 = *(const float4*)(arow + kc + 36);
        __syncthreads();

        bf16x8 af;
        af[0] = (__bf16)a00.x; af[1] = (__bf16)a00.y;
        af[2] = (__bf16)a00.z; af[3] = (__bf16)a00.w;
        af[4] = (__bf16)a01.x; af[5] = (__bf16)a01.y;
        af[6] = (__bf16)a01.z; af[7] = (__bf16)a01.w;
        #pragma unroll
        for (int i = 0; i < 8; i++) {
            bf16x8 bfrag = *(const bf16x8*)(Bt + (i * 16 + col) * 128 + ((grp ^ sw) * 16));
            acc[i] = __builtin_amdgcn_mfma_f32_16x16x32_bf16(af, bfrag, acc[i], 0, 0, 0);
        }
        af[0] = (__bf16)a10.x; af[1] = (__bf16)a10.y;
        af[2] = (__bf16)a10.z; af[3] = (__bf16)a10.w;
        af[4] = (__bf16)a11.x; af[5] = (__bf16)a11.y;
        af[6] = (__bf16)a11.z; af[7] = (__bf16)a11.w;
        #pragma unroll
        for (int i = 0; i < 8; i++) {
            bf16x8 bfrag = *(const bf16x8*)(Bt + (i * 16 + col) * 128 + (((4 + grp) ^ sw) * 16));
            acc[i] = __builtin_amdgcn_mfma_f32_16x16x32_bf16(af, bfrag, acc[i], 0, 0, 0);
        }
        __syncthreads();
    }

    // epilogue: tanh(acc + bias) . out_w, reduce over a
    float s[4] = {0.f, 0.f, 0.f, 0.f};
    #pragma unroll
    for (int i = 0; i < 8; i++) {
        int a = i * 16 + col;
        float ow = out_w[a];
        float bias = pdec[b * A_ + a];
        #pragma unroll
        for (int r = 0; r < 4; r++) {
            float v = acc[i][r] + bias;
            v = fminf(fmaxf(v, -15.f), 15.f);
            float e = __expf(2.f * v);
            s[r] += ow * ((e - 1.f) / (e + 1.f));
        }
    }
    #pragma unroll
    for (int r = 0; r < 4; r++) {
        s[r] += __shfl_xor(s[r], 1, 64);
        s[r] += __shfl_xor(s[r], 2, 64);
        s[r] += __shfl_xor(s[r], 4, 64);
        s[r] += __shfl_xor(s[r], 8, 64);
    }
    if (col == 0) {
        #pragma unroll
        for (int r = 0; r < 4; r++) {
            int t = t0 + wv * 16 + grp * 4 + r;
            if (t < T_) score[b * T_ + t] = s[r];
        }
    }
}

// ---------------------------------------------------------------------------
// Kernel 3: per-b masked max/sum of exp(score) -> minv[b]={m, 1/sum};
// also zeroes ctx[b][:].
// ---------------------------------------------------------------------------
__global__ __launch_bounds__(256) void smax_kernel(
    const float* __restrict__ score, const int* __restrict__ lengths,
    float* __restrict__ minv, float* __restrict__ ctx)
{
    int b = blockIdx.x;
    int tid = threadIdx.x;
    if (tid < 128)
        *(float4*)(ctx + b * DE_ + tid * 4) = make_float4(0.f, 0.f, 0.f, 0.f);
    int len = lengths[b];
    __shared__ float redm[4], reds[4];

    float m = -1e30f;
    for (int t = tid; t < T_; t += 256)
        if (t < len) m = fmaxf(m, score[b * T_ + t]);
    #pragma unroll
    for (int off = 1; off < 64; off <<= 1) m = fmaxf(m, __shfl_xor(m, off, 64));
    if ((tid & 63) == 0) redm[tid >> 6] = m;
    __syncthreads();
    m = fmaxf(fmaxf(redm[0], redm[1]), fmaxf(redm[2], redm[3]));

    float sum = 0.f;
    for (int t = tid; t < T_; t += 256)
        if (t < len) sum += __expf(score[b * T_ + t] - m);
    #pragma unroll
    for (int off = 1; off < 64; off <<= 1) sum += __shfl_xor(sum, off, 64);
    if ((tid & 63) == 0) reds[tid >> 6] = sum;
    __syncthreads();
    if (tid == 0) {
        sum = reds[0] + reds[1] + reds[2] + reds[3];
        minv[2 * b] = m;
        minv[2 * b + 1] = 1.f / sum;
    }
}

// ---------------------------------------------------------------------------
// Kernel 4: context + att write. grid (32 t-chunks of 63, B).
// w = exp(score-m)/sum computed in-kernel; att[b][t] written here.
// ---------------------------------------------------------------------------
#define NCH 32
#define CCH 63
__global__ __launch_bounds__(256) void context_kernel(
    const float* __restrict__ enc, const float* __restrict__ score,
    const float* __restrict__ minv, const int* __restrict__ lengths,
    float* __restrict__ att, float* __restrict__ ctx)
{
    int b = blockIdx.y;
    int tstart = blockIdx.x * CCH;
    int len = lengths[b];
    float m = minv[2 * b], inv = minv[2 * b + 1];
    __shared__ float w_s[CCH];
    for (int j = threadIdx.x; j < CCH; j += 256) {
        int t = tstart + j;
        float w = 0.f;
        if (t < len) w = __expf(score[b * T_ + t] - m) * inv;
        if (t < T_) att[b * T_ + t] = w;
        w_s[j] = w;
    }
    __syncthreads();

    int tend = tstart + CCH < len ? tstart + CCH : len;
    if (tstart >= tend) return;
    int n = tend - tstart;
    int half = threadIdx.x >> 7;                 // 2 rows per step
    int d0 = (threadIdx.x & 127) * 4;
    const float* base = enc + ((size_t)(b * T_ + tstart)) * DE_ + d0;
    float ax = 0.f, ay = 0.f, az = 0.f, aw = 0.f;
    #pragma unroll 4
    for (int t = half; t < n; t += 2) {
        float w = w_s[t];
        float4 v = *(const float4*)(base + (size_t)t * DE_);
        ax += w * v.x; ay += w * v.y; az += w * v.z; aw += w * v.w;
    }
    atomicAdd(&ctx[b * DE_ + d0 + 0], ax);
    atomicAdd(&ctx[b * DE_ + d0 + 1], ay);
    atomicAdd(&ctx[b * DE_ + d0 + 2], az);
    atomicAdd(&ctx[b * DE_ + d0 + 3], aw);
}

// ---------------------------------------------------------------------------
extern "C" void kernel_launch(void* const* d_in, const int* in_sizes, int n_in,
                              void* d_out, int out_size, void* d_ws, size_t ws_size,
                              hipStream_t stream)
{
    const float* input_enc   = (const float*)d_in[0];
    const int*   enc_lengths = (const int*)d_in[1];
    const float* input_dec   = (const float*)d_in[2];
    const float* prev_att    = (const float*)d_in[3];
    const float* conv_w      = (const float*)d_in[4];
    const float* enc_w       = (const float*)d_in[5];
    const float* dec_w       = (const float*)d_in[6];
    const float* att_w       = (const float*)d_in[7];
    const float* att_b       = (const float*)d_in[8];
    const float* out_w       = (const float*)d_in[9];

    float* out = (float*)d_out;                 // [0:B*DE) context, [B*DE:) att_weight
    char* ws = (char*)d_ws;
    float*  pdec   = (float*)ws;                              // B*A floats (16 KB)
    float*  score  = (float*)(ws + 16384);                    // B*T floats (256 KB)
    __bf16* enc_bf = (__bf16*)(ws + 16384 + 256000);          // A*DE bf16 (128 KB)
    __bf16* att_bf = (__bf16*)(ws + 16384 + 256000 + 131072); // A*FN bf16 (8 KB)
    float*  minv   = pdec;    // pdec region is dead after score_kernel; reuse

    prep_kernel<<<192, 256, 0, stream>>>(enc_w, att_w, input_dec, dec_w, att_b,
                                         enc_bf, att_bf, pdec);

    dim3 sgrid((T_ + BT - 1) / BT, B_);
    score_kernel<<<sgrid, 256, 0, stream>>>(input_enc, enc_bf, prev_att, conv_w,
                                            att_bf, pdec, out_w, score);

    smax_kernel<<<B_, 256, 0, stream>>>(score, enc_lengths, minv, out);

    dim3 cgrid(NCH, B_);
    context_kernel<<<cgrid, 256, 0, stream>>>(input_enc, score, minv, enc_lengths,
                                              out + B_ * DE_, out);
}

// Round 4
// 225.878 us; speedup vs baseline: 1.6019x; 1.0884x over previous
//
#include <hip/hip_runtime.h>
#include <hip/hip_bf16.h>
#include <math.h>

#define B_ 32
#define T_ 2000
#define DE_ 512
#define DD_ 1024
#define A_ 128
#define FN_ 32
#define FS_ 16
#define KW_ (2*FS_+1)   // 33

typedef __bf16 bf16x8 __attribute__((ext_vector_type(8)));
typedef __bf16 bf16x4 __attribute__((ext_vector_type(4)));
typedef float f32x4 __attribute__((ext_vector_type(4)));

#define BT 64            // t-rows per score block
#define LSTR 40          // loc tile LDS stride (bf16)

// async global->LDS, 16 B per lane; dest = lds base (wave-uniform) + lane*16
__device__ __forceinline__ void load_lds16(const void* g, void* l) {
    __builtin_amdgcn_global_load_lds(
        (const __attribute__((address_space(1))) unsigned int*)g,
        (__attribute__((address_space(3))) unsigned int*)l, 16, 0, 0);
}

// ---------------------------------------------------------------------------
// Kernel 1: prep.
//  blocks   0..63 : enc_w/att_w fp32->bf16
//  blocks  64..191: pdec[b][a] = att_b[a] + input_dec[b] . dec_w[a]
//  blocks 192..208: zero ctx_un (16384 f) + denom (32 f)
// ---------------------------------------------------------------------------
__global__ __launch_bounds__(256) void prep_kernel(
    const float* __restrict__ enc_w, const float* __restrict__ att_w,
    const float* __restrict__ input_dec, const float* __restrict__ dec_w,
    const float* __restrict__ att_b,
    __bf16* __restrict__ enc_bf, __bf16* __restrict__ att_bf,
    float* __restrict__ pdec, float* __restrict__ ctx_un /* denom follows */)
{
    int bx = blockIdx.x, tid = threadIdx.x;
    if (bx < 64) {
        int i = bx * 256 + tid;                         // float4 index
        float4 v = ((const float4*)enc_w)[i];
        bf16x4 o;
        o[0] = (__bf16)v.x; o[1] = (__bf16)v.y; o[2] = (__bf16)v.z; o[3] = (__bf16)v.w;
        *(bf16x4*)(enc_bf + (size_t)i * 4) = o;
        if (i < (A_ * FN_) / 4) {
            float4 w = ((const float4*)att_w)[i];
            bf16x4 p;
            p[0] = (__bf16)w.x; p[1] = (__bf16)w.y; p[2] = (__bf16)w.z; p[3] = (__bf16)w.w;
            *(bf16x4*)(att_bf + (size_t)i * 4) = p;
        }
    } else if (bx < 192) {
        int pb = bx - 64;                               // 0..127
        int b  = pb >> 2;
        int a0 = (pb & 3) * 32;
        int al = tid >> 3;                              // 0..31
        int kg = tid & 7;                               // 0..7
        int a  = a0 + al;
        const float4* w = (const float4*)(dec_w + (size_t)a * DD_);
        const float4* x = (const float4*)(input_dec + (size_t)b * DD_);
        float acc = 0.f;
        #pragma unroll 8
        for (int j = 0; j < 32; j++) {
            int i4 = kg + j * 8;
            float4 wv = w[i4], xv = x[i4];
            acc += wv.x * xv.x + wv.y * xv.y + wv.z * xv.z + wv.w * xv.w;
        }
        acc += __shfl_xor(acc, 1, 64);
        acc += __shfl_xor(acc, 2, 64);
        acc += __shfl_xor(acc, 4, 64);
        if (kg == 0) pdec[b * A_ + a] = acc + att_b[a];
    } else {
        int idx = (bx - 192) * 256 + tid;               // float4 index
        if (idx < (B_ * DE_ + B_) / 4 + 1)              // 16416 floats -> 4104 f4
            ((float4*)ctx_un)[idx] = make_float4(0.f, 0.f, 0.f, 0.f);
    }
}

// ---------------------------------------------------------------------------
// Kernel 2: score + context partials. One block = (b, 64 t-rows).
// B (enc_bf) chunk staged to LDS via global_load_lds w/ XOR source swizzle;
// A rows direct from global fp32. loc-projection folded into the MFMA acc.
// Max-free softmax: w = exp(score - M), M = sum|out_w| (data-independent
// upper bound, identical in every block). Block then accumulates its own
// 64x512 tile (L2-hot) into ctx_un via atomics, and sum(w) into denom.
// ---------------------------------------------------------------------------
__global__ __launch_bounds__(256, 4) void score_kernel(
    const float* __restrict__ input_enc, const __bf16* __restrict__ enc_bf,
    const float* __restrict__ prev_att,  const float* __restrict__ conv_w,
    const __bf16* __restrict__ att_bf,   const float* __restrict__ pdec,
    const float* __restrict__ out_w,     const int* __restrict__ lengths,
    float* __restrict__ wbuf, float* __restrict__ ctx_un,
    float* __restrict__ denom)
{
    __shared__ __align__(16) char Bt[16384];     // B chunk: 128 rows x 64 k bf16
    __shared__ float pa_s[BT + 2 * FS_];
    __shared__ float cw_s[KW_ * FN_];
    __shared__ __align__(16) __bf16 loc_s[BT * LSTR];
    __shared__ float w_s[BT];

    const int tid = threadIdx.x;
    const int b  = blockIdx.y;
    const int t0 = blockIdx.x * BT;
    const int len = lengths[b];

    for (int j = tid; j < BT + 2 * FS_; j += 256) {
        int t = t0 - FS_ + j;
        pa_s[j] = (t >= 0 && t < T_) ? prev_att[b * T_ + t] : 0.f;
    }
    for (int idx = tid; idx < FN_ * KW_; idx += 256) {
        int f = idx / KW_, k = idx % KW_;
        cw_s[k * FN_ + f] = conv_w[idx];
    }
    __syncthreads();

    {   // conv -> loc (bf16)
        int f = tid & 31, r0 = tid >> 5;
        for (int r = r0; r < BT; r += 8) {
            float acc = 0.f;
            #pragma unroll
            for (int k = 0; k < KW_; k++) acc += pa_s[r + k] * cw_s[k * FN_ + f];
            loc_s[r * LSTR + f] = (__bf16)acc;
        }
    }
    __syncthreads();

    const int lane = tid & 63;
    const int wv   = tid >> 6;
    const int col  = lane & 15;
    const int grp  = lane >> 4;
    const int rowb = wv * 16 + col;
    const int t_row = t0 + rowb;
    const int t_clamp = t_row < T_ ? t_row : T_ - 1;
    const int sw = (col & 7);                    // XOR swizzle key for ds reads

    f32x4 acc[8];
    const f32x4 zero = (f32x4){0.f, 0.f, 0.f, 0.f};

    {   // loc-projection MFMA (K=32=FN)
        bf16x8 afrag = *(const bf16x8*)(loc_s + rowb * LSTR + grp * 8);
        #pragma unroll
        for (int i = 0; i < 8; i++) {
            bf16x8 bfrag = *(const bf16x8*)(att_bf + (size_t)(i * 16 + col) * FN_ + grp * 8);
            acc[i] = __builtin_amdgcn_mfma_f32_16x16x32_bf16(afrag, bfrag, zero, 0, 0, 0);
        }
    }

    const float* arow = input_enc + ((size_t)(b * T_ + t_clamp)) * DE_ + grp * 8;

    for (int kc = 0; kc < DE_; kc += 64) {
        // stage B chunk: slot s -> row r = s>>3, phys chunk cp = s&7;
        // source logical chunk c = cp ^ (r&7)  (XOR bank swizzle)
        #pragma unroll
        for (int j = 0; j < 4; j++) {
            int s  = j * 256 + tid;
            int r  = s >> 3;
            int cp = s & 7;
            int c  = cp ^ (r & 7);
            load_lds16(enc_bf + (size_t)r * DE_ + kc + c * 8,
                       Bt + j * 4096 + wv * 1024);
        }
        float4 a00 = *(const float4*)(arow + kc);
        float4 a01 = *(const float4*)(arow + kc + 4);
        float4 a10 = *(const float4*)(arow + kc + 32);
        float4 a11 = *(const float4*)(arow + kc + 36);
        __syncthreads();

        bf16x8 af;
        af[0] = (__bf16)a00.x; af[1] = (__bf16)a00.y;
        af[2] = (__bf16)a00.z; af[3] = (__bf16)a00.w;
        af[4] = (__bf16)a01.x; af[5] = (__bf16)a01.y;
        af[6] = (__bf16)a01.z; af[7] = (__bf16)a01.w;
        #pragma unroll
        for (int i = 0; i < 8; i++) {
            bf16x8 bfrag = *(const bf16x8*)(Bt + (i * 16 + col) * 128 + ((grp ^ sw) * 16));
            acc[i] = __builtin_amdgcn_mfma_f32_16x16x32_bf16(af, bfrag, acc[i], 0, 0, 0);
        }
        af[0] = (__bf16)a10.x; af[1] = (__bf16)a10.y;
        af[2] = (__bf16)a10.z; af[3] = (__bf16)a10.w;
        af[4] = (__bf16)a11.x; af[5] = (__bf16)a11.y;
        af[6] = (__bf16)a11.z; af[7] = (__bf16)a11.w;
        #pragma unroll
        for (int i = 0; i < 8; i++) {
            bf16x8 bfrag = *(const bf16x8*)(Bt + (i * 16 + col) * 128 + (((4 + grp) ^ sw) * 16));
            acc[i] = __builtin_amdgcn_mfma_f32_16x16x32_bf16(af, bfrag, acc[i], 0, 0, 0);
        }
        __syncthreads();
    }

    // epilogue: s = tanh(acc + bias) . out_w over a; M = sum|out_w|
    float s[4] = {0.f, 0.f, 0.f, 0.f};
    float Mabs = 0.f;
    #pragma unroll
    for (int i = 0; i < 8; i++) {
        int a = i * 16 + col;
        float ow = out_w[a];
        Mabs += fabsf(ow);
        float bias = pdec[b * A_ + a];
        #pragma unroll
        for (int r = 0; r < 4; r++) {
            float v = acc[i][r] + bias;
            v = fminf(fmaxf(v, -15.f), 15.f);
            float e = __expf(2.f * v);
            s[r] += ow * ((e - 1.f) / (e + 1.f));
        }
    }
    #pragma unroll
    for (int r = 0; r < 4; r++) {
        s[r] += __shfl_xor(s[r], 1, 64);
        s[r] += __shfl_xor(s[r], 2, 64);
        s[r] += __shfl_xor(s[r], 4, 64);
        s[r] += __shfl_xor(s[r], 8, 64);
    }
    Mabs += __shfl_xor(Mabs, 1, 64);
    Mabs += __shfl_xor(Mabs, 2, 64);
    Mabs += __shfl_xor(Mabs, 4, 64);
    Mabs += __shfl_xor(Mabs, 8, 64);    // same value & rounding in every wave

    if (col == 0) {
        #pragma unroll
        for (int r = 0; r < 4; r++) {
            int rl = wv * 16 + grp * 4 + r;
            int t = t0 + rl;
            float w = 0.f;
            if (t < len) w = __expf(s[r] - Mabs);
            w_s[rl] = w;
            if (t < T_) wbuf[b * T_ + t] = w;
        }
    }
    __syncthreads();

    // denominator partial (wave 0)
    if (tid < 64) {
        float w = w_s[tid];
        w += __shfl_xor(w, 1, 64);
        w += __shfl_xor(w, 2, 64);
        w += __shfl_xor(w, 4, 64);
        w += __shfl_xor(w, 8, 64);
        w += __shfl_xor(w, 16, 64);
        w += __shfl_xor(w, 32, 64);
        if (tid == 0) atomicAdd(&denom[b], w);
    }

    // context partial: tile rows are L2-hot from the GEMM reads
    int n_eff = len - t0;
    if (n_eff > BT) n_eff = BT;
    if (n_eff > 0) {
        int d0 = tid * 2;
        const float* ebase = input_enc + ((size_t)(b * T_ + t0)) * DE_ + d0;
        float cx = 0.f, cy = 0.f;
        #pragma unroll 8
        for (int t = 0; t < n_eff; t++) {
            float w = w_s[t];
            float2 v = *(const float2*)(ebase + (size_t)t * DE_);
            cx += w * v.x;
            cy += w * v.y;
        }
        atomicAdd(&ctx_un[b * DE_ + d0 + 0], cx);
        atomicAdd(&ctx_un[b * DE_ + d0 + 1], cy);
    }
}

// ---------------------------------------------------------------------------
// Kernel 3: finalize. blocks 0..63: att = wbuf/denom; 64..79: ctx = ctx_un/denom
// ---------------------------------------------------------------------------
__global__ __launch_bounds__(256) void finalize_kernel(
    const float* __restrict__ wbuf, const float* __restrict__ ctx_un,
    const float* __restrict__ denom, float* __restrict__ out)
{
    int bx = blockIdx.x, tid = threadIdx.x;
    if (bx < 64) {
        int i4 = bx * 256 + tid;
        if (i4 < (B_ * T_) / 4) {
            int b = i4 / (T_ / 4);
            float inv = 1.f / denom[b];
            float4 w = ((const float4*)wbuf)[i4];
            w.x *= inv; w.y *= inv; w.z *= inv; w.w *= inv;
            ((float4*)(out + B_ * DE_))[i4] = w;
        }
    } else {
        int j = (bx - 64) * 256 + tid;          // 0..4095
        int b = j / (DE_ / 4);
        float inv = 1.f / denom[b];
        float4 c = ((const float4*)ctx_un)[j];
        c.x *= inv; c.y *= inv; c.z *= inv; c.w *= inv;
        ((float4*)out)[j] = c;
    }
}

// ---------------------------------------------------------------------------
extern "C" void kernel_launch(void* const* d_in, const int* in_sizes, int n_in,
                              void* d_out, int out_size, void* d_ws, size_t ws_size,
                              hipStream_t stream)
{
    const float* input_enc   = (const float*)d_in[0];
    const int*   enc_lengths = (const int*)d_in[1];
    const float* input_dec   = (const float*)d_in[2];
    const float* prev_att    = (const float*)d_in[3];
    const float* conv_w      = (const float*)d_in[4];
    const float* enc_w       = (const float*)d_in[5];
    const float* dec_w       = (const float*)d_in[6];
    const float* att_w       = (const float*)d_in[7];
    const float* att_b       = (const float*)d_in[8];
    const float* out_w       = (const float*)d_in[9];

    float* out = (float*)d_out;                 // [0:B*DE) context, [B*DE:) att_weight
    char* ws = (char*)d_ws;
    float*  pdec   = (float*)ws;                              // 4096 f   (16384 B)
    float*  wbuf   = (float*)(ws + 16384);                    // 64000 f  (256000 B)
    __bf16* enc_bf = (__bf16*)(ws + 272384);                  // A*DE bf16 (131072 B)
    __bf16* att_bf = (__bf16*)(ws + 403456);                  // A*FN bf16 (8192 B)
    float*  ctx_un = (float*)(ws + 411648);                   // 16384 f  (65536 B)
    float*  denom  = (float*)(ws + 477184);                   // 32 f

    prep_kernel<<<209, 256, 0, stream>>>(enc_w, att_w, input_dec, dec_w, att_b,
                                         enc_bf, att_bf, pdec, ctx_un);

    dim3 sgrid((T_ + BT - 1) / BT, B_);
    score_kernel<<<sgrid, 256, 0, stream>>>(input_enc, enc_bf, prev_att, conv_w,
                                            att_bf, pdec, out_w, enc_lengths,
                                            wbuf, ctx_un, denom);

    finalize_kernel<<<80, 256, 0, stream>>>(wbuf, ctx_un, denom, out);
}